// Round 6
// baseline (70.459 us; speedup 1.0000x reference)
//
#include <hip/hip_runtime.h>

// Depthwise cross-correlation, B*C = 32768 planes: x[32][32] (*) k[8][8] -> out[25][25].
// softmax(weight) sums to 1.0 -> output == correlation; weight unused.
//
// bf16 + v_dot2_f32_bf16, thread = (plane, 5x4 output tile), 35 threads/plane.
// x in LDS as ONE packed-bf16 copy (dword = cols 2i,2i+1), row stride 16 dwords,
// 8B-granule XOR swizzle (g ^= row&7) on write AND read. Odd output columns use
// in-register alignbit-shifted pairs (xs), so no second phase copy is needed.
// Per thread: 36 ds_read_b64 + 8 ds_read_b128 (taps), 640 dot2, 60 alignbit.

#define NPLANES (128 * 256)
#define PPB 7
#define XSTR 536                    // x plane stride (dwords): 512 + overrun/pad (row31 granule15 -> 527)
#define KTB (PPB * XSTR)            // taps base, 3752 (%4==0 for b128)
#define KTS 36                      // taps plane stride (dwords); %32=4 de-aliases planes
#define LDS_DW (KTB + PPB * KTS)    // 4004 dw = 16016 B
#define OH 25
#define OW 25

__device__ __forceinline__ unsigned cvt_pk_bf16(float a, float b) {
    unsigned r;  // lo = bf16(a), hi = bf16(b)
    asm("v_cvt_pk_bf16_f32 %0, %1, %2" : "=v"(r) : "v"(a), "v"(b));
    return r;
}
__device__ __forceinline__ void dot2(float& acc, unsigned x2, unsigned k2) {
    asm("v_dot2_f32_bf16 %0, %1, %2, %0" : "+v"(acc) : "v"(x2), "v"(k2));
}

__global__ __launch_bounds__(256)
void dwxcorr_kernel(const float* __restrict__ x,
                    const float* __restrict__ kern,
                    float* __restrict__ out) {
    __shared__ unsigned ldsu[LDS_DW];
    const int tid = threadIdx.x;
    const int plane0 = blockIdx.x * PPB;
    const int nplane = (NPLANES - plane0 < PPB) ? (NPLANES - plane0) : PPB;

    // ---- Stage x: unit = one float4 (cols 4*c4..4*c4+3 of a row) -> one b64 write ----
    const int nf4 = nplane * 256;
    for (int idx = tid; idx < nf4; idx += 256) {
        const int pb  = idx >> 8;
        const int o4  = idx & 255;
        const int row = o4 >> 3;
        const int c4  = o4 & 7;              // granule index (2 packed dwords)
        const float4 v =
            reinterpret_cast<const float4*>(x)[(size_t)(plane0 + pb) * 256 + o4];
        const unsigned p0 = cvt_pk_bf16(v.x, v.y);
        const unsigned p1 = cvt_pk_bf16(v.z, v.w);
        const int off = pb * XSTR + row * 16 + ((c4 ^ (row & 7)) << 1);
        *reinterpret_cast<uint2*>(&ldsu[off]) = make_uint2(p0, p1);
    }
    // ---- Stage taps: float4 -> 2 packed dwords; flat (ky*8+kx)/2 order ----
    if (tid < nplane * 16) {
        const int pl = tid >> 4;
        const int o4 = tid & 15;
        const float4 v =
            *reinterpret_cast<const float4*>(kern + (size_t)(plane0 + pl) * 64 + o4 * 4);
        unsigned* kb = &ldsu[KTB + pl * KTS + o4 * 2];
        kb[0] = cvt_pk_bf16(v.x, v.y);
        kb[1] = cvt_pk_bf16(v.z, v.w);
    }
    __syncthreads();

    const int pb = tid / 35;
    if (pb >= nplane) return;               // tids 245..255 idle (+ tail block)
    const int t  = tid % 35;
    const int rg = t / 7;                   // output rows rg*5 .. rg*5+4
    const int cg = t % 7;                   // output cols cg*4 .. cg*4+3 (cg=6: col 24 only)

    // ---- All 64 taps as 32 packed dwords (b128 reads, broadcast per plane) ----
    unsigned kt[32];
    {
        const unsigned* kp = &ldsu[KTB + pb * KTS];
#pragma unroll
        for (int i = 0; i < 8; ++i) {
            const uint4 q = *reinterpret_cast<const uint4*>(kp + 4 * i);
            kt[4*i+0] = q.x; kt[4*i+1] = q.y; kt[4*i+2] = q.z; kt[4*i+3] = q.w;
        }
    }

    float acc[5][4];
#pragma unroll
    for (int i = 0; i < 5; ++i)
#pragma unroll
        for (int j = 0; j < 4; ++j) acc[i][j] = 0.f;

    const int xb = pb * XSTR;
#pragma unroll
    for (int ar = 0; ar < 12; ++ar) {
        const int row = rg * 5 + ar;         // 0..31
        const int rb  = xb + row * 16;
        const int swz = row & 7;
        // 3 b64 reads: granules cg..cg+2 (cg=6,j=2 -> granule 8 overruns into
        // row pad region; garbage feeds only masked-out columns >=25).
        unsigned xr[6];
#pragma unroll
        for (int j = 0; j < 3; ++j) {
            const uint2 q =
                *reinterpret_cast<const uint2*>(&ldsu[rb + (((cg + j) ^ swz) << 1)]);
            xr[2*j]   = q.x;                 // cols 4(cg+j)+0,1
            xr[2*j+1] = q.y;                 // cols 4(cg+j)+2,3
        }
        // Shifted pairs for odd output columns: xs[i] = (cols c0+2i+1, c0+2i+2)
        unsigned xs[5];
#pragma unroll
        for (int i = 0; i < 5; ++i) xs[i] = (xr[i] >> 16) | (xr[i+1] << 16);

#pragma unroll
        for (int ky = 0; ky < 8; ++ky) {
            const int oy = ar - ky;          // compile-time with full unroll
            if (oy >= 0 && oy < 5) {
#pragma unroll
                for (int tt = 0; tt < 4; ++tt) {
                    const unsigned kv = kt[ky * 4 + tt];
                    dot2(acc[oy][0], xr[tt],     kv);   // col c0   (even)
                    dot2(acc[oy][1], xs[tt],     kv);   // col c0+1 (odd)
                    dot2(acc[oy][2], xr[tt + 1], kv);   // col c0+2 (even)
                    dot2(acc[oy][3], xs[tt + 1], kv);   // col c0+3 (odd)
                }
            }
        }
    }

    // ---- Store 5x4 tile (cols >=25 of cg=6 dropped); scalar stores (odd strides) ----
    float* op = out + (size_t)(plane0 + pb) * (OH * OW);
    const int c0 = cg * 4;
#pragma unroll
    for (int oy = 0; oy < 5; ++oy) {
        const int orow = rg * 5 + oy;
#pragma unroll
        for (int oc = 0; oc < 4; ++oc) {
            const int col = c0 + oc;
            if (col < OW) op[orow * OW + col] = acc[oy][oc];
        }
    }
}

extern "C" void kernel_launch(void* const* d_in, const int* in_sizes, int n_in,
                              void* d_out, int out_size, void* d_ws, size_t ws_size,
                              hipStream_t stream) {
    const float* x = (const float*)d_in[0];
    const float* k = (const float*)d_in[1];
    // d_in[2] (weight) unused: softmax weights sum to exactly 1.
    float* out = (float*)d_out;
    const int nblocks = (NPLANES + PPB - 1) / PPB;   // 4682
    dwxcorr_kernel<<<nblocks, 256, 0, stream>>>(x, k, out);
}

// Round 7
// 66.505 us; speedup vs baseline: 1.0595x; 1.0595x over previous
//
#include <hip/hip_runtime.h>

// Depthwise cross-correlation, B*C = 32768 planes: x[32][32] (*) k[8][8] -> out[25][25].
// softmax(weight) sums to 1.0 -> output == correlation; weight unused.
//
// bf16 + v_dot2_f32_bf16, thread = (plane, 5x4 output tile), 35 threads/plane.
// x in LDS as ONE packed-bf16 copy (dword = cols 2i,2i+1), row stride 16 dwords,
// 8B-granule XOR swizzle (g ^= row&7) on write AND read. Odd output columns via
// in-register shifted pairs (xs). Taps processed in TWO ky-halves of 16 packed
// dwords (#pragma unroll 1) so the live set (~55 VGPR) fits even the compiler's
// 8-waves/SIMD target -- round 6's allocator (VGPR=48) sank kt[32] back into
// the loop as per-use LDS re-reads, serializing the inner loop.

#define NPLANES (128 * 256)
#define PPB 7
#define XSTR 536                    // x plane stride (dwords)
#define KTB (PPB * XSTR)            // taps base, 3752 (%4==0 for b128)
#define KTS 36                      // taps plane stride (dwords)
#define LDS_DW (KTB + PPB * KTS)    // 4004 dw = 16016 B
#define OH 25
#define OW 25

__device__ __forceinline__ unsigned cvt_pk_bf16(float a, float b) {
    unsigned r;  // lo = bf16(a), hi = bf16(b)
    asm("v_cvt_pk_bf16_f32 %0, %1, %2" : "=v"(r) : "v"(a), "v"(b));
    return r;
}
__device__ __forceinline__ void dot2(float& acc, unsigned x2, unsigned k2) {
    asm("v_dot2_f32_bf16 %0, %1, %2, %0" : "+v"(acc) : "v"(x2), "v"(k2));
}

__global__ __launch_bounds__(256)
void dwxcorr_kernel(const float* __restrict__ x,
                    const float* __restrict__ kern,
                    float* __restrict__ out) {
    __shared__ unsigned ldsu[LDS_DW];
    const int tid = threadIdx.x;
    const int plane0 = blockIdx.x * PPB;
    const int nplane = (NPLANES - plane0 < PPB) ? (NPLANES - plane0) : PPB;

    // ---- Stage x: one float4 (4 cols of a row) -> one b64 swizzled write ----
    const int nf4 = nplane * 256;
    for (int idx = tid; idx < nf4; idx += 256) {
        const int pb  = idx >> 8;
        const int o4  = idx & 255;
        const int row = o4 >> 3;
        const int c4  = o4 & 7;              // 8B granule index
        const float4 v =
            reinterpret_cast<const float4*>(x)[(size_t)(plane0 + pb) * 256 + o4];
        const unsigned p0 = cvt_pk_bf16(v.x, v.y);
        const unsigned p1 = cvt_pk_bf16(v.z, v.w);
        const int off = pb * XSTR + row * 16 + ((c4 ^ (row & 7)) << 1);
        *reinterpret_cast<uint2*>(&ldsu[off]) = make_uint2(p0, p1);
    }
    // ---- Stage taps: float4 -> 2 packed dwords; flat (ky*8+kx)/2 order ----
    if (tid < nplane * 16) {
        const int pl = tid >> 4;
        const int o4 = tid & 15;
        const float4 v =
            *reinterpret_cast<const float4*>(kern + (size_t)(plane0 + pl) * 64 + o4 * 4);
        unsigned* kb = &ldsu[KTB + pl * KTS + o4 * 2];
        kb[0] = cvt_pk_bf16(v.x, v.y);
        kb[1] = cvt_pk_bf16(v.z, v.w);
    }
    __syncthreads();

    const int pb = tid / 35;
    if (pb >= nplane) return;               // tids 245..255 idle (+ tail block)
    const int t  = tid % 35;
    const int rg = t / 7;                   // output rows rg*5 .. rg*5+4
    const int cg = t % 7;                   // output cols cg*4 .. cg*4+3 (cg=6: col 24 only)

    float acc[5][4];
#pragma unroll
    for (int i = 0; i < 5; ++i)
#pragma unroll
        for (int j = 0; j < 4; ++j) acc[i][j] = 0.f;

    const int xb = pb * XSTR;
    const unsigned* kp = &ldsu[KTB + pb * KTS];

    // ---- Two ky-halves, kept sequential: only 16 tap dwords live at a time ----
#pragma unroll 1
    for (int h = 0; h < 2; ++h) {
        unsigned kt[16];                     // taps ky = 4h .. 4h+3
#pragma unroll
        for (int i = 0; i < 4; ++i) {
            const uint4 q = *reinterpret_cast<const uint4*>(kp + h * 16 + 4 * i);
            kt[4*i+0] = q.x; kt[4*i+1] = q.y; kt[4*i+2] = q.z; kt[4*i+3] = q.w;
        }
#pragma unroll
        for (int a = 0; a < 8; ++a) {
            const int row = rg * 5 + h * 4 + a;   // 0..31
            const int rb  = xb + row * 16;
            const int swz = row & 7;
            // 3 b64 reads: granules cg..cg+2 (cg=6,j=2 overruns into row pad;
            // garbage feeds only masked-out columns >=25).
            unsigned xr[6];
#pragma unroll
            for (int j = 0; j < 3; ++j) {
                const uint2 q =
                    *reinterpret_cast<const uint2*>(&ldsu[rb + (((cg + j) ^ swz) << 1)]);
                xr[2*j]   = q.x;
                xr[2*j+1] = q.y;
            }
            // Shifted pairs for odd output columns
            unsigned xs[5];
#pragma unroll
            for (int i = 0; i < 5; ++i) xs[i] = (xr[i] >> 16) | (xr[i+1] << 16);

#pragma unroll
            for (int kyl = 0; kyl < 4; ++kyl) {
                const int oy = a - kyl;           // compile-time
                if (oy >= 0 && oy < 5) {
#pragma unroll
                    for (int tt = 0; tt < 4; ++tt) {
                        const unsigned kv = kt[kyl * 4 + tt];
                        dot2(acc[oy][0], xr[tt],     kv);
                        dot2(acc[oy][1], xs[tt],     kv);
                        dot2(acc[oy][2], xr[tt + 1], kv);
                        dot2(acc[oy][3], xs[tt + 1], kv);
                    }
                }
            }
        }
    }

    // ---- Store 5x4 tile (cols >=25 of cg=6 dropped) ----
    float* op = out + (size_t)(plane0 + pb) * (OH * OW);
    const int c0 = cg * 4;
#pragma unroll
    for (int oy = 0; oy < 5; ++oy) {
        const int orow = rg * 5 + oy;
#pragma unroll
        for (int oc = 0; oc < 4; ++oc) {
            const int col = c0 + oc;
            if (col < OW) op[orow * OW + col] = acc[oy][oc];
        }
    }
}

extern "C" void kernel_launch(void* const* d_in, const int* in_sizes, int n_in,
                              void* d_out, int out_size, void* d_ws, size_t ws_size,
                              hipStream_t stream) {
    const float* x = (const float*)d_in[0];
    const float* k = (const float*)d_in[1];
    // d_in[2] (weight) unused: softmax weights sum to exactly 1.
    float* out = (float*)d_out;
    const int nblocks = (NPLANES + PPB - 1) / PPB;   // 4682
    dwxcorr_kernel<<<nblocks, 256, 0, stream>>>(x, k, out);
}